// Round 16
// baseline (509.244 us; speedup 1.0000x reference)
//
#include <hip/hip_runtime.h>
#include <hip/hip_bf16.h>

#define NUM_ENT   30000
#define NUM_ATTR  10000
#define NUM_NODES 40000
#define NUM_TYPES 10
#define HIDDEN    200
#define KPAD      224      // HIDDEN padded for MFMA K (big GEMM) / N (decoder)
#define XP        416      // decoder K: 401 padded to 13*32
#define NPAD2     30208    // NUM_ENT padded to 118*256 (256-col gemm tiles)
#define N_EDGES   600000
#define BATCH     4096
#define XDIM      401      // 2*HIDDEN + 1
#define RRELU_SLOPE 0.22916666666666666f

using bf16x8 = __attribute__((ext_vector_type(8))) short;
using f32x4  = __attribute__((ext_vector_type(4))) float;
typedef __hip_bfloat16 bf16;

__device__ inline float bf2f(ushort u) { return __uint_as_float((unsigned)u << 16); }

// ---------------------------------------------------------------------------
// Convert ent||attr (f32) to concatenated bf16 h0b[40000][200].
// ---------------------------------------------------------------------------
__global__ void k_cvt(const float* __restrict__ ent, const float* __restrict__ attr,
                      ushort* __restrict__ h0b) {
    int i4 = blockIdx.x * blockDim.x + threadIdx.x;      // float4 index
    if (i4 >= NUM_NODES * HIDDEN / 4) return;
    int base = i4 * 4;
    const float* src = (base < NUM_ENT * HIDDEN) ? ent + base
                                                 : attr + (base - NUM_ENT * HIDDEN);
    float4 v = *reinterpret_cast<const float4*>(src);
    ushort4 o;
    o.x = __bfloat16_as_ushort(__float2bfloat16(v.x));
    o.y = __bfloat16_as_ushort(__float2bfloat16(v.y));
    o.z = __bfloat16_as_ushort(__float2bfloat16(v.z));
    o.w = __bfloat16_as_ushort(__float2bfloat16(v.w));
    *reinterpret_cast<ushort4*>(h0b + base) = o;
}

// ---------------------------------------------------------------------------
// caps from norm (cap = round(1/norm) >= count), exclusive scan -> offsets
// + cursor init. Single block, 1024 threads.
// ---------------------------------------------------------------------------
__global__ __launch_bounds__(1024) void k_prep(const float* __restrict__ norm,
                                               int* __restrict__ offsets,
                                               int* __restrict__ cursor) {
    __shared__ int part[1024];
    int t = threadIdx.x;
    const int CH = (NUM_ENT + 1023) / 1024;     // 30
    int base = t * CH;
    int caps[CH];
    int s = 0;
    for (int i = 0; i < CH; ++i) {
        int idx = base + i;
        int c = 0;
        if (idx < NUM_ENT) c = (int)(1.0f / norm[idx] + 0.5f);
        caps[i] = c;
        s += c;
    }
    part[t] = s;
    __syncthreads();
    for (int off = 1; off < 1024; off <<= 1) {
        int v = (t >= off) ? part[t - off] : 0;
        __syncthreads();
        part[t] += v;
        __syncthreads();
    }
    int run = (t == 0) ? 0 : part[t - 1];
    for (int i = 0; i < CH; ++i) {
        int idx = base + i;
        if (idx < NUM_ENT) {
            offsets[idx] = run;
            cursor[idx]  = run;
            run += caps[i];
        }
    }
}

// ---------------------------------------------------------------------------
// Bucket edges by destination; store packed (src<<4 | type).
// ---------------------------------------------------------------------------
__global__ void k_place(const int* __restrict__ edst, const int* __restrict__ esrc,
                        const int* __restrict__ etype, int* __restrict__ cursor,
                        int* __restrict__ sorted) {
    int e = blockIdx.x * blockDim.x + threadIdx.x;
    if (e < N_EDGES) {
        int d = edst[e];
        if (d < NUM_ENT) {
            int p = atomicAdd(&cursor[d], 1);
            sorted[p] = (esrc[e] << 4) | etype[e];
        }
    }
}

// ---------------------------------------------------------------------------
// TWO waves per node; sub-wave partials combined via LDS. No atomics.
// ---------------------------------------------------------------------------
__global__ void k_aggregate(const ushort* __restrict__ h0b, const float* __restrict__ w,
                            const int* __restrict__ offsets, const int* __restrict__ cursor,
                            const int* __restrict__ sorted, const float* __restrict__ norm,
                            bf16* __restrict__ S) {
    __shared__ float wl[NUM_TYPES * HIDDEN];    // 8 KB
    __shared__ float part[2][200];
    for (int i = threadIdx.x; i < NUM_TYPES * HIDDEN; i += blockDim.x)
        wl[i] = w[i];
    __syncthreads();

    int wid  = threadIdx.x >> 6;
    int lane = threadIdx.x & 63;
    int ln   = wid >> 1;                        // local node 0/1
    int sub  = wid & 1;                         // sub-wave within node
    int n    = blockIdx.x * 2 + ln;
    bool live = (n < NUM_ENT);
    bool act  = lane < 50;
    int  c    = lane * 4;

    float4 a0 = make_float4(0, 0, 0, 0), a1 = a0, a2 = a0, a3 = a0;
    if (live) {
        int beg = offsets[n], end = cursor[n];
        int mid = beg + ((end - beg + 1) >> 1);
        int lo = sub ? mid : beg;
        int hi = sub ? end : mid;
        int e = lo;
        for (; e + 4 <= hi; e += 4) {
            int r0 = sorted[e + 0], r1 = sorted[e + 1], r2 = sorted[e + 2], r3 = sorted[e + 3];
            if (act) {
                ushort4 h0 = *reinterpret_cast<const ushort4*>(h0b + (size_t)(r0 >> 4) * HIDDEN + c);
                ushort4 h1 = *reinterpret_cast<const ushort4*>(h0b + (size_t)(r1 >> 4) * HIDDEN + c);
                ushort4 h2 = *reinterpret_cast<const ushort4*>(h0b + (size_t)(r2 >> 4) * HIDDEN + c);
                ushort4 h3 = *reinterpret_cast<const ushort4*>(h0b + (size_t)(r3 >> 4) * HIDDEN + c);
                const float* w0 = &wl[(r0 & 15) * HIDDEN + c];
                const float* w1 = &wl[(r1 & 15) * HIDDEN + c];
                const float* w2 = &wl[(r2 & 15) * HIDDEN + c];
                const float* w3 = &wl[(r3 & 15) * HIDDEN + c];
                a0.x += bf2f(h0.x) * w0[0]; a0.y += bf2f(h0.y) * w0[1];
                a0.z += bf2f(h0.z) * w0[2]; a0.w += bf2f(h0.w) * w0[3];
                a1.x += bf2f(h1.x) * w1[0]; a1.y += bf2f(h1.y) * w1[1];
                a1.z += bf2f(h1.z) * w1[2]; a1.w += bf2f(h1.w) * w1[3];
                a2.x += bf2f(h2.x) * w2[0]; a2.y += bf2f(h2.y) * w2[1];
                a2.z += bf2f(h2.z) * w2[2]; a2.w += bf2f(h2.w) * w2[3];
                a3.x += bf2f(h3.x) * w3[0]; a3.y += bf2f(h3.y) * w3[1];
                a3.z += bf2f(h3.z) * w3[2]; a3.w += bf2f(h3.w) * w3[3];
            }
        }
        for (; e < hi; ++e) {
            int r0 = sorted[e];
            if (act) {
                ushort4 h0 = *reinterpret_cast<const ushort4*>(h0b + (size_t)(r0 >> 4) * HIDDEN + c);
                const float* w0 = &wl[(r0 & 15) * HIDDEN + c];
                a0.x += bf2f(h0.x) * w0[0]; a0.y += bf2f(h0.y) * w0[1];
                a0.z += bf2f(h0.z) * w0[2]; a0.w += bf2f(h0.w) * w0[3];
            }
        }
    }
    float4 acc = make_float4(a0.x + a1.x + a2.x + a3.x,
                             a0.y + a1.y + a2.y + a3.y,
                             a0.z + a1.z + a2.z + a3.z,
                             a0.w + a1.w + a2.w + a3.w);
    if (live && sub == 1 && act)
        *reinterpret_cast<float4*>(&part[ln][c]) = acc;
    __syncthreads();

    if (sub == 0) {
        if (!live) {                            // S zero-pad rows (30000..30207)
            if (lane < KPAD / 4) {
                bf16 z4[4] = {};
                *reinterpret_cast<uint2*>(S + (size_t)n * KPAD + lane * 4) =
                    *reinterpret_cast<uint2*>(z4);
            }
        } else if (act) {
            float4 o = *reinterpret_cast<float4*>(&part[ln][c]);
            float nm = norm[n];
            float v0 = (acc.x + o.x) * nm;
            float v1 = (acc.y + o.y) * nm;
            float v2 = (acc.z + o.z) * nm;
            float v3 = (acc.w + o.w) * nm;
            v0 = (v0 >= 0.f) ? v0 : RRELU_SLOPE * v0;
            v1 = (v1 >= 0.f) ? v1 : RRELU_SLOPE * v1;
            v2 = (v2 >= 0.f) ? v2 : RRELU_SLOPE * v2;
            v3 = (v3 >= 0.f) ? v3 : RRELU_SLOPE * v3;
            bf16 t4[4] = {__float2bfloat16(v0), __float2bfloat16(v1),
                          __float2bfloat16(v2), __float2bfloat16(v3)};
            *reinterpret_cast<uint2*>(S + (size_t)n * KPAD + lane * 4) =
                *reinterpret_cast<uint2*>(t4);
        } else if (lane < KPAD / 4) {           // K-pad 200..223 -> zero
            bf16 z4[4] = {};
            *reinterpret_cast<uint2*>(S + (size_t)n * KPAD + lane * 4) =
                *reinterpret_cast<uint2*>(z4);
        }
    }
}

// ---------------------------------------------------------------------------
// Fused: blocks [0,BATCH) build X rows; blocks [BATCH, BATCH+KPAD) build Wb.
// ---------------------------------------------------------------------------
__global__ void k_build_XW(const bf16* __restrict__ S, const float* __restrict__ rel_emb,
                           const float* __restrict__ time_emb, const float* __restrict__ dec_W,
                           const int* __restrict__ batch, bf16* __restrict__ X,
                           bf16* __restrict__ Wb) {
    int b = blockIdx.x;
    if (b < BATCH) {
        int m = b;
        int e  = batch[m * 4 + 0];
        int rl = batch[m * 4 + 1];
        int tr = batch[m * 4 + 3];
        float tv = time_emb[tr / 24];
        for (int c = threadIdx.x; c < XP; c += 256) {
            float v;
            if (c < HIDDEN) {
                v = tanhf(__bfloat162float(S[(size_t)e * KPAD + c]));
            } else if (c < 2 * HIDDEN) {
                v = rel_emb[(size_t)rl * HIDDEN + (c - HIDDEN)];
            } else if (c == 2 * HIDDEN) {
                v = tv;
            } else {
                v = 0.f;
            }
            X[(size_t)m * XP + c] = __float2bfloat16(v);
        }
    } else {
        int n = b - BATCH;
        for (int c = threadIdx.x; c < XP; c += 256) {
            float v = (n < HIDDEN && c < XDIM) ? dec_W[(size_t)n * XDIM + c] : 0.f;
            Wb[(size_t)n * XP + c] = __float2bfloat16(v);
        }
    }
}

// ---------------------------------------------------------------------------
// Y[4096][224] bf16 = relu( X(4096x416) . Wb^T(416x224) + b ), MFMA 16x16x32.
// ---------------------------------------------------------------------------
__global__ __launch_bounds__(256) void k_dec_gemm(const bf16* __restrict__ Xb,
                                                  const bf16* __restrict__ Wbb,
                                                  const float* __restrict__ dec_b,
                                                  bf16* __restrict__ Y) {
    int wid  = threadIdx.x >> 6;
    int lane = threadIdx.x & 63;
    int row0 = blockIdx.x * 64 + wid * 16;
    int rsel = lane & 15;
    int koff = (lane >> 4) * 8;

    const short* Xp = reinterpret_cast<const short*>(Xb);
    const short* Wp = reinterpret_cast<const short*>(Wbb);

    f32x4 acc[14] = {};
#pragma unroll
    for (int kt = 0; kt < 13; ++kt) {
        int kbase = kt * 32 + koff;
        bf16x8 a = *reinterpret_cast<const bf16x8*>(Xp + (size_t)(row0 + rsel) * XP + kbase);
#pragma unroll
        for (int j = 0; j < 14; ++j) {
            bf16x8 b = *reinterpret_cast<const bf16x8*>(Wp + (size_t)(j * 16 + rsel) * XP + kbase);
            acc[j] = __builtin_amdgcn_mfma_f32_16x16x32_bf16(a, b, acc[j], 0, 0, 0);
        }
    }

    int crow = (lane >> 4) * 4;     // C/D: col=lane&15, row=(lane>>4)*4+r
    int ccol = lane & 15;
#pragma unroll
    for (int j = 0; j < 14; ++j) {
        int col = j * 16 + ccol;
        float bias = (col < HIDDEN) ? dec_b[col] : 0.f;
#pragma unroll
        for (int r = 0; r < 4; ++r) {
            int row = row0 + crow + r;
            float v = fmaxf(acc[j][r] + bias, 0.f);
            Y[(size_t)row * KPAD + col] = __float2bfloat16(v);
        }
    }
}

// ---------------------------------------------------------------------------
// out[4096][30000] (f32) = Y(4096x224) . S^T(224x30208pad), bf16 MFMA.
// THIN-TILE round: 32x256 tiles (grid 118x128, xtile fast) -> resident block
// cohort covers a ~33MB contiguous sliding window (was ~130MB with 256-row
// bands), approximating the fill kernel's dense sweeping write window.
// 4 waves; single-barrier block-coop epilogue; 1KB-contiguous nt stores.
// ---------------------------------------------------------------------------
__global__ __launch_bounds__(256) void k_gemm(const bf16* __restrict__ Yb,
                                              const bf16* __restrict__ Sb,
                                              float* __restrict__ out) {
    __shared__ float eb[32 * 260];              // 33,280 B

    int bid   = blockIdx.x;                 // 0..15103
    int xtile = bid % 118;                  // N tile (FAST -> dense window)
    int ytile = bid / 118;                  // 32-row band, 0..127

    int tid  = threadIdx.x;
    int wid  = tid >> 6;                    // 0..3
    int lane = tid & 63;
    int row0 = ytile * 32;
    int col0 = xtile * 256 + wid * 64;
    int rsel = lane & 15;
    int koff = (lane >> 4) * 8;

    const short* Yp = reinterpret_cast<const short*>(Yb);
    const short* Sp = reinterpret_cast<const short*>(Sb);

    f32x4 acc[2][4] = {};
#pragma unroll
    for (int kt = 0; kt < 7; ++kt) {
        int kbase = kt * 32 + koff;
        bf16x8 a[2], b[4];
#pragma unroll
        for (int i = 0; i < 2; ++i)
            a[i] = *reinterpret_cast<const bf16x8*>(Yp + (size_t)(row0 + i * 16 + rsel) * KPAD + kbase);
#pragma unroll
        for (int j = 0; j < 4; ++j)
            b[j] = *reinterpret_cast<const bf16x8*>(Sp + (size_t)(col0 + j * 16 + rsel) * KPAD + kbase);
#pragma unroll
        for (int i = 0; i < 2; ++i)
#pragma unroll
            for (int j = 0; j < 4; ++j)
                acc[i][j] = __builtin_amdgcn_mfma_f32_16x16x32_bf16(a[i], b[j], acc[i][j], 0, 0, 0);
    }

    // Deposit whole 32x256 tile (waves own disjoint column strips), 1 barrier.
    int hi16 = lane >> 4;
    int lo16 = lane & 15;
#pragma unroll
    for (int i = 0; i < 2; ++i)
#pragma unroll
        for (int j = 0; j < 4; ++j)
#pragma unroll
            for (int r = 0; r < 4; ++r)
                eb[(i * 16 + hi16 * 4 + r) * 260 + wid * 64 + j * 16 + lo16] = acc[i][j][r];
    __syncthreads();

    // Cooperative store: each wave-sweep writes one contiguous 1KB row segment.
    int gcol = xtile * 256 + lane * 4;
    bool ok  = gcol < NUM_ENT;              // 30000%4==0: all-or-nothing per f32x4
#pragma unroll
    for (int s = 0; s < 8; ++s) {
        int lr = s * 4 + wid;               // 0..31
        f32x4 v = *reinterpret_cast<f32x4*>(&eb[lr * 260 + lane * 4]);
        if (ok)
            __builtin_nontemporal_store(v,
                reinterpret_cast<f32x4*>(&out[(size_t)(row0 + lr) * NUM_ENT + gcol]));
    }
}

// ---------------------------------------------------------------------------
extern "C" void kernel_launch(void* const* d_in, const int* in_sizes, int n_in,
                              void* d_out, int out_size, void* d_ws, size_t ws_size,
                              hipStream_t stream) {
    const float* ent_emb  = (const float*)d_in[0];
    const float* attr_emb = (const float*)d_in[1];
    const float* rel_emb  = (const float*)d_in[2];
    const float* time_emb = (const float*)d_in[3];
    const float* rgcn_w   = (const float*)d_in[4];
    const float* dec_W    = (const float*)d_in[5];
    const float* dec_b    = (const float*)d_in[6];
    const float* norm     = (const float*)d_in[7];
    const int*   esrc     = (const int*)d_in[8];
    const int*   edst     = (const int*)d_in[9];
    const int*   etype    = (const int*)d_in[10];
    const int*   batch    = (const int*)d_in[11];

    char* ws = (char*)d_ws;
    bf16*   S      = (bf16*)ws;                           // 30208*224*2 = 13,533,184 B
    bf16*   Y      = (bf16*)(ws + 13533184);              //  1,835,008 B
    int*    offs   = (int*)(ws + 15368192);               //    120,064 B
    int*    cursor = (int*)(ws + 15488256);               //    120,064 B
    int*    sorted = (int*)(ws + 15608320);               //  2,520,000 B
    bf16*   X      = (bf16*)(ws + 18128320);              //  3,407,872 B (4096x416)
    bf16*   Wb     = (bf16*)(ws + 21536192);              //    186,368 B (224x416)
    ushort* h0b    = (ushort*)(ws + 21722560);            // 16,000,000 B (40000x200)

    k_cvt  <<<(NUM_NODES * HIDDEN / 4 + 255) / 256, 256, 0, stream>>>(ent_emb, attr_emb, h0b);
    k_prep <<<1, 1024, 0, stream>>>(norm, offs, cursor);
    k_place<<<(N_EDGES + 255) / 256, 256, 0, stream>>>(edst, esrc, etype, cursor, sorted);
    k_aggregate<<<NPAD2 / 2, 256, 0, stream>>>(h0b, rgcn_w, offs, cursor, sorted, norm, S);
    k_build_XW<<<BATCH + KPAD, 256, 0, stream>>>(S, rel_emb, time_emb, dec_W, batch, X, Wb);
    k_dec_gemm<<<BATCH / 64, 256, 0, stream>>>(X, Wb, dec_b, Y);
    k_gemm<<<118 * 128, 256, 0, stream>>>(Y, S, (float*)d_out);
}

// Round 17
// 366.787 us; speedup vs baseline: 1.3884x; 1.3884x over previous
//
#include <hip/hip_runtime.h>
#include <hip/hip_bf16.h>

#define NUM_ENT   30000
#define NUM_ATTR  10000
#define NUM_NODES 40000
#define NUM_TYPES 10
#define HIDDEN    200
#define KPAD      224      // HIDDEN padded for MFMA K (big GEMM) / N (decoder)
#define XP        416      // decoder K: 401 padded to 13*32
#define NPAD2     30208    // NUM_ENT padded to 118*256 (256-col gemm tiles)
#define N_EDGES   600000
#define BATCH     4096
#define XDIM      401      // 2*HIDDEN + 1
#define RRELU_SLOPE 0.22916666666666666f

using bf16x8 = __attribute__((ext_vector_type(8))) short;
using f32x4  = __attribute__((ext_vector_type(4))) float;
typedef __hip_bfloat16 bf16;

__device__ inline float bf2f(ushort u) { return __uint_as_float((unsigned)u << 16); }

// ---------------------------------------------------------------------------
// Convert ent||attr (f32) to concatenated bf16 h0b[40000][200].
// ---------------------------------------------------------------------------
__global__ void k_cvt(const float* __restrict__ ent, const float* __restrict__ attr,
                      ushort* __restrict__ h0b) {
    int i4 = blockIdx.x * blockDim.x + threadIdx.x;      // float4 index
    if (i4 >= NUM_NODES * HIDDEN / 4) return;
    int base = i4 * 4;
    const float* src = (base < NUM_ENT * HIDDEN) ? ent + base
                                                 : attr + (base - NUM_ENT * HIDDEN);
    float4 v = *reinterpret_cast<const float4*>(src);
    ushort4 o;
    o.x = __bfloat16_as_ushort(__float2bfloat16(v.x));
    o.y = __bfloat16_as_ushort(__float2bfloat16(v.y));
    o.z = __bfloat16_as_ushort(__float2bfloat16(v.z));
    o.w = __bfloat16_as_ushort(__float2bfloat16(v.w));
    *reinterpret_cast<ushort4*>(h0b + base) = o;
}

// ---------------------------------------------------------------------------
// caps from norm (cap = round(1/norm) >= count), exclusive scan -> offsets
// + cursor init. Single block, 1024 threads.
// ---------------------------------------------------------------------------
__global__ __launch_bounds__(1024) void k_prep(const float* __restrict__ norm,
                                               int* __restrict__ offsets,
                                               int* __restrict__ cursor) {
    __shared__ int part[1024];
    int t = threadIdx.x;
    const int CH = (NUM_ENT + 1023) / 1024;     // 30
    int base = t * CH;
    int caps[CH];
    int s = 0;
    for (int i = 0; i < CH; ++i) {
        int idx = base + i;
        int c = 0;
        if (idx < NUM_ENT) c = (int)(1.0f / norm[idx] + 0.5f);
        caps[i] = c;
        s += c;
    }
    part[t] = s;
    __syncthreads();
    for (int off = 1; off < 1024; off <<= 1) {
        int v = (t >= off) ? part[t - off] : 0;
        __syncthreads();
        part[t] += v;
        __syncthreads();
    }
    int run = (t == 0) ? 0 : part[t - 1];
    for (int i = 0; i < CH; ++i) {
        int idx = base + i;
        if (idx < NUM_ENT) {
            offsets[idx] = run;
            cursor[idx]  = run;
            run += caps[i];
        }
    }
}

// ---------------------------------------------------------------------------
// Bucket edges by destination; store packed (src<<4 | type).
// ---------------------------------------------------------------------------
__global__ void k_place(const int* __restrict__ edst, const int* __restrict__ esrc,
                        const int* __restrict__ etype, int* __restrict__ cursor,
                        int* __restrict__ sorted) {
    int e = blockIdx.x * blockDim.x + threadIdx.x;
    if (e < N_EDGES) {
        int d = edst[e];
        if (d < NUM_ENT) {
            int p = atomicAdd(&cursor[d], 1);
            sorted[p] = (esrc[e] << 4) | etype[e];
        }
    }
}

// ---------------------------------------------------------------------------
// TWO waves per node; sub-wave partials combined via LDS. No atomics.
// ---------------------------------------------------------------------------
__global__ void k_aggregate(const ushort* __restrict__ h0b, const float* __restrict__ w,
                            const int* __restrict__ offsets, const int* __restrict__ cursor,
                            const int* __restrict__ sorted, const float* __restrict__ norm,
                            bf16* __restrict__ S) {
    __shared__ float wl[NUM_TYPES * HIDDEN];    // 8 KB
    __shared__ float part[2][200];
    for (int i = threadIdx.x; i < NUM_TYPES * HIDDEN; i += blockDim.x)
        wl[i] = w[i];
    __syncthreads();

    int wid  = threadIdx.x >> 6;
    int lane = threadIdx.x & 63;
    int ln   = wid >> 1;                        // local node 0/1
    int sub  = wid & 1;                         // sub-wave within node
    int n    = blockIdx.x * 2 + ln;
    bool live = (n < NUM_ENT);
    bool act  = lane < 50;
    int  c    = lane * 4;

    float4 a0 = make_float4(0, 0, 0, 0), a1 = a0, a2 = a0, a3 = a0;
    if (live) {
        int beg = offsets[n], end = cursor[n];
        int mid = beg + ((end - beg + 1) >> 1);
        int lo = sub ? mid : beg;
        int hi = sub ? end : mid;
        int e = lo;
        for (; e + 4 <= hi; e += 4) {
            int r0 = sorted[e + 0], r1 = sorted[e + 1], r2 = sorted[e + 2], r3 = sorted[e + 3];
            if (act) {
                ushort4 h0 = *reinterpret_cast<const ushort4*>(h0b + (size_t)(r0 >> 4) * HIDDEN + c);
                ushort4 h1 = *reinterpret_cast<const ushort4*>(h0b + (size_t)(r1 >> 4) * HIDDEN + c);
                ushort4 h2 = *reinterpret_cast<const ushort4*>(h0b + (size_t)(r2 >> 4) * HIDDEN + c);
                ushort4 h3 = *reinterpret_cast<const ushort4*>(h0b + (size_t)(r3 >> 4) * HIDDEN + c);
                const float* w0 = &wl[(r0 & 15) * HIDDEN + c];
                const float* w1 = &wl[(r1 & 15) * HIDDEN + c];
                const float* w2 = &wl[(r2 & 15) * HIDDEN + c];
                const float* w3 = &wl[(r3 & 15) * HIDDEN + c];
                a0.x += bf2f(h0.x) * w0[0]; a0.y += bf2f(h0.y) * w0[1];
                a0.z += bf2f(h0.z) * w0[2]; a0.w += bf2f(h0.w) * w0[3];
                a1.x += bf2f(h1.x) * w1[0]; a1.y += bf2f(h1.y) * w1[1];
                a1.z += bf2f(h1.z) * w1[2]; a1.w += bf2f(h1.w) * w1[3];
                a2.x += bf2f(h2.x) * w2[0]; a2.y += bf2f(h2.y) * w2[1];
                a2.z += bf2f(h2.z) * w2[2]; a2.w += bf2f(h2.w) * w2[3];
                a3.x += bf2f(h3.x) * w3[0]; a3.y += bf2f(h3.y) * w3[1];
                a3.z += bf2f(h3.z) * w3[2]; a3.w += bf2f(h3.w) * w3[3];
            }
        }
        for (; e < hi; ++e) {
            int r0 = sorted[e];
            if (act) {
                ushort4 h0 = *reinterpret_cast<const ushort4*>(h0b + (size_t)(r0 >> 4) * HIDDEN + c);
                const float* w0 = &wl[(r0 & 15) * HIDDEN + c];
                a0.x += bf2f(h0.x) * w0[0]; a0.y += bf2f(h0.y) * w0[1];
                a0.z += bf2f(h0.z) * w0[2]; a0.w += bf2f(h0.w) * w0[3];
            }
        }
    }
    float4 acc = make_float4(a0.x + a1.x + a2.x + a3.x,
                             a0.y + a1.y + a2.y + a3.y,
                             a0.z + a1.z + a2.z + a3.z,
                             a0.w + a1.w + a2.w + a3.w);
    if (live && sub == 1 && act)
        *reinterpret_cast<float4*>(&part[ln][c]) = acc;
    __syncthreads();

    if (sub == 0) {
        if (!live) {                            // S zero-pad rows (30000..30207)
            if (lane < KPAD / 4) {
                bf16 z4[4] = {};
                *reinterpret_cast<uint2*>(S + (size_t)n * KPAD + lane * 4) =
                    *reinterpret_cast<uint2*>(z4);
            }
        } else if (act) {
            float4 o = *reinterpret_cast<float4*>(&part[ln][c]);
            float nm = norm[n];
            float v0 = (acc.x + o.x) * nm;
            float v1 = (acc.y + o.y) * nm;
            float v2 = (acc.z + o.z) * nm;
            float v3 = (acc.w + o.w) * nm;
            v0 = (v0 >= 0.f) ? v0 : RRELU_SLOPE * v0;
            v1 = (v1 >= 0.f) ? v1 : RRELU_SLOPE * v1;
            v2 = (v2 >= 0.f) ? v2 : RRELU_SLOPE * v2;
            v3 = (v3 >= 0.f) ? v3 : RRELU_SLOPE * v3;
            bf16 t4[4] = {__float2bfloat16(v0), __float2bfloat16(v1),
                          __float2bfloat16(v2), __float2bfloat16(v3)};
            *reinterpret_cast<uint2*>(S + (size_t)n * KPAD + lane * 4) =
                *reinterpret_cast<uint2*>(t4);
        } else if (lane < KPAD / 4) {           // K-pad 200..223 -> zero
            bf16 z4[4] = {};
            *reinterpret_cast<uint2*>(S + (size_t)n * KPAD + lane * 4) =
                *reinterpret_cast<uint2*>(z4);
        }
    }
}

// ---------------------------------------------------------------------------
// Fused: blocks [0,BATCH) build X rows; blocks [BATCH, BATCH+KPAD) build Wb.
// ---------------------------------------------------------------------------
__global__ void k_build_XW(const bf16* __restrict__ S, const float* __restrict__ rel_emb,
                           const float* __restrict__ time_emb, const float* __restrict__ dec_W,
                           const int* __restrict__ batch, bf16* __restrict__ X,
                           bf16* __restrict__ Wb) {
    int b = blockIdx.x;
    if (b < BATCH) {
        int m = b;
        int e  = batch[m * 4 + 0];
        int rl = batch[m * 4 + 1];
        int tr = batch[m * 4 + 3];
        float tv = time_emb[tr / 24];
        for (int c = threadIdx.x; c < XP; c += 256) {
            float v;
            if (c < HIDDEN) {
                v = tanhf(__bfloat162float(S[(size_t)e * KPAD + c]));
            } else if (c < 2 * HIDDEN) {
                v = rel_emb[(size_t)rl * HIDDEN + (c - HIDDEN)];
            } else if (c == 2 * HIDDEN) {
                v = tv;
            } else {
                v = 0.f;
            }
            X[(size_t)m * XP + c] = __float2bfloat16(v);
        }
    } else {
        int n = b - BATCH;
        for (int c = threadIdx.x; c < XP; c += 256) {
            float v = (n < HIDDEN && c < XDIM) ? dec_W[(size_t)n * XDIM + c] : 0.f;
            Wb[(size_t)n * XP + c] = __float2bfloat16(v);
        }
    }
}

// ---------------------------------------------------------------------------
// Y[4096][224] bf16 = relu( X(4096x416) . Wb^T(416x224) + b ), MFMA 16x16x32.
// ---------------------------------------------------------------------------
__global__ __launch_bounds__(256) void k_dec_gemm(const bf16* __restrict__ Xb,
                                                  const bf16* __restrict__ Wbb,
                                                  const float* __restrict__ dec_b,
                                                  bf16* __restrict__ Y) {
    int wid  = threadIdx.x >> 6;
    int lane = threadIdx.x & 63;
    int row0 = blockIdx.x * 64 + wid * 16;
    int rsel = lane & 15;
    int koff = (lane >> 4) * 8;

    const short* Xp = reinterpret_cast<const short*>(Xb);
    const short* Wp = reinterpret_cast<const short*>(Wbb);

    f32x4 acc[14] = {};
#pragma unroll
    for (int kt = 0; kt < 13; ++kt) {
        int kbase = kt * 32 + koff;
        bf16x8 a = *reinterpret_cast<const bf16x8*>(Xp + (size_t)(row0 + rsel) * XP + kbase);
#pragma unroll
        for (int j = 0; j < 14; ++j) {
            bf16x8 b = *reinterpret_cast<const bf16x8*>(Wp + (size_t)(j * 16 + rsel) * XP + kbase);
            acc[j] = __builtin_amdgcn_mfma_f32_16x16x32_bf16(a, b, acc[j], 0, 0, 0);
        }
    }

    int crow = (lane >> 4) * 4;     // C/D: col=lane&15, row=(lane>>4)*4+r
    int ccol = lane & 15;
#pragma unroll
    for (int j = 0; j < 14; ++j) {
        int col = j * 16 + ccol;
        float bias = (col < HIDDEN) ? dec_b[col] : 0.f;
#pragma unroll
        for (int r = 0; r < 4; ++r) {
            int row = row0 + crow + r;
            float v = fmaxf(acc[j][r] + bias, 0.f);
            Y[(size_t)row * KPAD + col] = __float2bfloat16(v);
        }
    }
}

// ---------------------------------------------------------------------------
// out[4096][30000] (f32) = Y(4096x224) . S^T(224x30208pad), bf16 MFMA.
// 256x256 tile, 8 waves, row-band-major order, block-coop 1KB-contiguous
// epilogue. PLAIN stores this round (no nontemporal): R16's counters showed
// FETCH=886MB on the gemm — write-allocate RMW on output lines. nt bypasses
// L2 so 16B stores can't merge into full-line dirty evictions; plain stores
// merge in L2 and evict full lines with no allocate-fetch (the fill's path:
// 1.97GB written, 27KB fetched).
// ---------------------------------------------------------------------------
__global__ __launch_bounds__(512, 2) void k_gemm(const bf16* __restrict__ Yb,
                                                 const bf16* __restrict__ Sb,
                                                 float* __restrict__ out) {
    __shared__ float eb[32 * 260];              // 33,280 B block-wide bounce

    int bid   = blockIdx.x;                 // 0..1887
    int xtile = bid % 118;                  // N tile (FAST -> row-band concurrency)
    int ytile = bid / 118;                  // M tile (slow), 0..15

    int tid  = threadIdx.x;
    int wid  = tid >> 6;                    // 0..7
    int lane = tid & 63;
    int wm = wid >> 2, wn = wid & 3;
    int row0 = ytile * 256 + wm * 128;
    int col0 = xtile * 256 + wn * 64;
    int rsel = lane & 15;
    int koff = (lane >> 4) * 8;

    const short* Yp = reinterpret_cast<const short*>(Yb);
    const short* Sp = reinterpret_cast<const short*>(Sb);

    f32x4 acc[8][4] = {};
#pragma unroll
    for (int kt = 0; kt < 7; ++kt) {
        int kbase = kt * 32 + koff;
        bf16x8 a[8], b[4];
#pragma unroll
        for (int i = 0; i < 8; ++i)
            a[i] = *reinterpret_cast<const bf16x8*>(Yp + (size_t)(row0 + i * 16 + rsel) * KPAD + kbase);
#pragma unroll
        for (int j = 0; j < 4; ++j)
            b[j] = *reinterpret_cast<const bf16x8*>(Sp + (size_t)(col0 + j * 16 + rsel) * KPAD + kbase);
#pragma unroll
        for (int i = 0; i < 8; ++i)
#pragma unroll
            for (int j = 0; j < 4; ++j)
                acc[i][j] = __builtin_amdgcn_mfma_f32_16x16x32_bf16(a[i], b[j], acc[i][j], 0, 0, 0);
    }

    // Epilogue: 8 chunks of 32 rows. C/D layout col=lane&15, row=(lane>>4)*4+r.
    int hi16 = lane >> 4;
    int lo16 = lane & 15;
    int gcol = xtile * 256 + lane * 4;
    bool ok  = gcol < NUM_ENT;              // 30000%4==0: all-or-nothing per f32x4
    int rband = ytile * 256;

#pragma unroll
    for (int h = 0; h < 8; ++h) {
        if (h) __syncthreads();             // previous chunk's reads done
        if ((wid >> 2) == (h >> 2)) {       // owning half of the waves deposits
            int i0 = (h & 3) * 2;
#pragma unroll
            for (int ii = 0; ii < 2; ++ii)
#pragma unroll
                for (int j = 0; j < 4; ++j)
#pragma unroll
                    for (int r = 0; r < 4; ++r)
                        eb[(ii * 16 + hi16 * 4 + r) * 260 + wn * 64 + j * 16 + lo16]
                            = acc[i0 + ii][j][r];
        }
        __syncthreads();
        // cooperative store: wave = one contiguous 1KB row segment per sweep
#pragma unroll
        for (int s = 0; s < 4; ++s) {
            int lr = s * 8 + wid;           // 0..31
            f32x4 v = *reinterpret_cast<f32x4*>(&eb[lr * 260 + lane * 4]);
            if (ok)
                *reinterpret_cast<f32x4*>(&out[(size_t)(rband + h * 32 + lr) * NUM_ENT + gcol]) = v;
        }
    }
}

// ---------------------------------------------------------------------------
extern "C" void kernel_launch(void* const* d_in, const int* in_sizes, int n_in,
                              void* d_out, int out_size, void* d_ws, size_t ws_size,
                              hipStream_t stream) {
    const float* ent_emb  = (const float*)d_in[0];
    const float* attr_emb = (const float*)d_in[1];
    const float* rel_emb  = (const float*)d_in[2];
    const float* time_emb = (const float*)d_in[3];
    const float* rgcn_w   = (const float*)d_in[4];
    const float* dec_W    = (const float*)d_in[5];
    const float* dec_b    = (const float*)d_in[6];
    const float* norm     = (const float*)d_in[7];
    const int*   esrc     = (const int*)d_in[8];
    const int*   edst     = (const int*)d_in[9];
    const int*   etype    = (const int*)d_in[10];
    const int*   batch    = (const int*)d_in[11];

    char* ws = (char*)d_ws;
    bf16*   S      = (bf16*)ws;                           // 30208*224*2 = 13,533,184 B
    bf16*   Y      = (bf16*)(ws + 13533184);              //  1,835,008 B
    int*    offs   = (int*)(ws + 15368192);               //    120,064 B
    int*    cursor = (int*)(ws + 15488256);               //    120,064 B
    int*    sorted = (int*)(ws + 15608320);               //  2,520,000 B
    bf16*   X      = (bf16*)(ws + 18128320);              //  3,407,872 B (4096x416)
    bf16*   Wb     = (bf16*)(ws + 21536192);              //    186,368 B (224x416)
    ushort* h0b    = (ushort*)(ws + 21722560);            // 16,000,000 B (40000x200)

    k_cvt  <<<(NUM_NODES * HIDDEN / 4 + 255) / 256, 256, 0, stream>>>(ent_emb, attr_emb, h0b);
    k_prep <<<1, 1024, 0, stream>>>(norm, offs, cursor);
    k_place<<<(N_EDGES + 255) / 256, 256, 0, stream>>>(edst, esrc, etype, cursor, sorted);
    k_aggregate<<<NPAD2 / 2, 256, 0, stream>>>(h0b, rgcn_w, offs, cursor, sorted, norm, S);
    k_build_XW<<<BATCH + KPAD, 256, 0, stream>>>(S, rel_emb, time_emb, dec_W, batch, X, Wb);
    k_dec_gemm<<<BATCH / 64, 256, 0, stream>>>(X, Wb, dec_b, Y);
    k_gemm<<<118 * 16, 512, 0, stream>>>(Y, S, (float*)d_out);
}

// Round 18
// 343.823 us; speedup vs baseline: 1.4811x; 1.0668x over previous
//
#include <hip/hip_runtime.h>
#include <hip/hip_bf16.h>

#define NUM_ENT   30000
#define NUM_ATTR  10000
#define NUM_NODES 40000
#define NUM_TYPES 10
#define HIDDEN    200
#define KPAD      224      // HIDDEN padded for MFMA K (big GEMM) / N (decoder)
#define XP        416      // decoder K: 401 padded to 13*32
#define NPAD2     30208    // NUM_ENT padded to 118*256 (256-col gemm tiles)
#define N_EDGES   600000
#define BATCH     4096
#define XDIM      401      // 2*HIDDEN + 1
#define RRELU_SLOPE 0.22916666666666666f

using bf16x8 = __attribute__((ext_vector_type(8))) short;
using f32x4  = __attribute__((ext_vector_type(4))) float;
typedef __hip_bfloat16 bf16;

__device__ inline float bf2f(ushort u) { return __uint_as_float((unsigned)u << 16); }

// ---------------------------------------------------------------------------
// Fused: block 0 = prep (caps from norm -> exclusive scan -> offs+cursor);
// blocks 1.. = convert ent||attr (f32) to bf16 h0b[40000][200]. 1024 thr.
// ---------------------------------------------------------------------------
__global__ __launch_bounds__(1024) void k_cvt_prep(const float* __restrict__ ent,
                                                   const float* __restrict__ attr,
                                                   const float* __restrict__ norm,
                                                   ushort* __restrict__ h0b,
                                                   int* __restrict__ offsets,
                                                   int* __restrict__ cursor) {
    if (blockIdx.x == 0) {
        __shared__ int part[1024];
        int t = threadIdx.x;
        const int CH = (NUM_ENT + 1023) / 1024;     // 30
        int base = t * CH;
        int caps[CH];
        int s = 0;
        for (int i = 0; i < CH; ++i) {
            int idx = base + i;
            int c = 0;
            if (idx < NUM_ENT) c = (int)(1.0f / norm[idx] + 0.5f);
            caps[i] = c;
            s += c;
        }
        part[t] = s;
        __syncthreads();
        for (int off = 1; off < 1024; off <<= 1) {
            int v = (t >= off) ? part[t - off] : 0;
            __syncthreads();
            part[t] += v;
            __syncthreads();
        }
        int run = (t == 0) ? 0 : part[t - 1];
        for (int i = 0; i < CH; ++i) {
            int idx = base + i;
            if (idx < NUM_ENT) {
                offsets[idx] = run;
                cursor[idx]  = run;
                run += caps[i];
            }
        }
    } else {
        int i4 = (blockIdx.x - 1) * 1024 + threadIdx.x;  // float4 index
        if (i4 >= NUM_NODES * HIDDEN / 4) return;
        int base = i4 * 4;
        const float* src = (base < NUM_ENT * HIDDEN) ? ent + base
                                                     : attr + (base - NUM_ENT * HIDDEN);
        float4 v = *reinterpret_cast<const float4*>(src);
        ushort4 o;
        o.x = __bfloat16_as_ushort(__float2bfloat16(v.x));
        o.y = __bfloat16_as_ushort(__float2bfloat16(v.y));
        o.z = __bfloat16_as_ushort(__float2bfloat16(v.z));
        o.w = __bfloat16_as_ushort(__float2bfloat16(v.w));
        *reinterpret_cast<ushort4*>(h0b + base) = o;
    }
}

// ---------------------------------------------------------------------------
// Bucket edges by destination; store packed (src<<4 | type).
// ---------------------------------------------------------------------------
__global__ void k_place(const int* __restrict__ edst, const int* __restrict__ esrc,
                        const int* __restrict__ etype, int* __restrict__ cursor,
                        int* __restrict__ sorted) {
    int e = blockIdx.x * blockDim.x + threadIdx.x;
    if (e < N_EDGES) {
        int d = edst[e];
        if (d < NUM_ENT) {
            int p = atomicAdd(&cursor[d], 1);
            sorted[p] = (esrc[e] << 4) | etype[e];
        }
    }
}

// ---------------------------------------------------------------------------
// TWO waves per node; sub-wave partials combined via LDS. No atomics.
// ---------------------------------------------------------------------------
__global__ void k_aggregate(const ushort* __restrict__ h0b, const float* __restrict__ w,
                            const int* __restrict__ offsets, const int* __restrict__ cursor,
                            const int* __restrict__ sorted, const float* __restrict__ norm,
                            bf16* __restrict__ S) {
    __shared__ float wl[NUM_TYPES * HIDDEN];    // 8 KB
    __shared__ float part[2][200];
    for (int i = threadIdx.x; i < NUM_TYPES * HIDDEN; i += blockDim.x)
        wl[i] = w[i];
    __syncthreads();

    int wid  = threadIdx.x >> 6;
    int lane = threadIdx.x & 63;
    int ln   = wid >> 1;                        // local node 0/1
    int sub  = wid & 1;                         // sub-wave within node
    int n    = blockIdx.x * 2 + ln;
    bool live = (n < NUM_ENT);
    bool act  = lane < 50;
    int  c    = lane * 4;

    float4 a0 = make_float4(0, 0, 0, 0), a1 = a0, a2 = a0, a3 = a0;
    if (live) {
        int beg = offsets[n], end = cursor[n];
        int mid = beg + ((end - beg + 1) >> 1);
        int lo = sub ? mid : beg;
        int hi = sub ? end : mid;
        int e = lo;
        for (; e + 4 <= hi; e += 4) {
            int r0 = sorted[e + 0], r1 = sorted[e + 1], r2 = sorted[e + 2], r3 = sorted[e + 3];
            if (act) {
                ushort4 h0 = *reinterpret_cast<const ushort4*>(h0b + (size_t)(r0 >> 4) * HIDDEN + c);
                ushort4 h1 = *reinterpret_cast<const ushort4*>(h0b + (size_t)(r1 >> 4) * HIDDEN + c);
                ushort4 h2 = *reinterpret_cast<const ushort4*>(h0b + (size_t)(r2 >> 4) * HIDDEN + c);
                ushort4 h3 = *reinterpret_cast<const ushort4*>(h0b + (size_t)(r3 >> 4) * HIDDEN + c);
                const float* w0 = &wl[(r0 & 15) * HIDDEN + c];
                const float* w1 = &wl[(r1 & 15) * HIDDEN + c];
                const float* w2 = &wl[(r2 & 15) * HIDDEN + c];
                const float* w3 = &wl[(r3 & 15) * HIDDEN + c];
                a0.x += bf2f(h0.x) * w0[0]; a0.y += bf2f(h0.y) * w0[1];
                a0.z += bf2f(h0.z) * w0[2]; a0.w += bf2f(h0.w) * w0[3];
                a1.x += bf2f(h1.x) * w1[0]; a1.y += bf2f(h1.y) * w1[1];
                a1.z += bf2f(h1.z) * w1[2]; a1.w += bf2f(h1.w) * w1[3];
                a2.x += bf2f(h2.x) * w2[0]; a2.y += bf2f(h2.y) * w2[1];
                a2.z += bf2f(h2.z) * w2[2]; a2.w += bf2f(h2.w) * w2[3];
                a3.x += bf2f(h3.x) * w3[0]; a3.y += bf2f(h3.y) * w3[1];
                a3.z += bf2f(h3.z) * w3[2]; a3.w += bf2f(h3.w) * w3[3];
            }
        }
        for (; e < hi; ++e) {
            int r0 = sorted[e];
            if (act) {
                ushort4 h0 = *reinterpret_cast<const ushort4*>(h0b + (size_t)(r0 >> 4) * HIDDEN + c);
                const float* w0 = &wl[(r0 & 15) * HIDDEN + c];
                a0.x += bf2f(h0.x) * w0[0]; a0.y += bf2f(h0.y) * w0[1];
                a0.z += bf2f(h0.z) * w0[2]; a0.w += bf2f(h0.w) * w0[3];
            }
        }
    }
    float4 acc = make_float4(a0.x + a1.x + a2.x + a3.x,
                             a0.y + a1.y + a2.y + a3.y,
                             a0.z + a1.z + a2.z + a3.z,
                             a0.w + a1.w + a2.w + a3.w);
    if (live && sub == 1 && act)
        *reinterpret_cast<float4*>(&part[ln][c]) = acc;
    __syncthreads();

    if (sub == 0) {
        if (!live) {                            // S zero-pad rows (30000..30207)
            if (lane < KPAD / 4) {
                bf16 z4[4] = {};
                *reinterpret_cast<uint2*>(S + (size_t)n * KPAD + lane * 4) =
                    *reinterpret_cast<uint2*>(z4);
            }
        } else if (act) {
            float4 o = *reinterpret_cast<float4*>(&part[ln][c]);
            float nm = norm[n];
            float v0 = (acc.x + o.x) * nm;
            float v1 = (acc.y + o.y) * nm;
            float v2 = (acc.z + o.z) * nm;
            float v3 = (acc.w + o.w) * nm;
            v0 = (v0 >= 0.f) ? v0 : RRELU_SLOPE * v0;
            v1 = (v1 >= 0.f) ? v1 : RRELU_SLOPE * v1;
            v2 = (v2 >= 0.f) ? v2 : RRELU_SLOPE * v2;
            v3 = (v3 >= 0.f) ? v3 : RRELU_SLOPE * v3;
            bf16 t4[4] = {__float2bfloat16(v0), __float2bfloat16(v1),
                          __float2bfloat16(v2), __float2bfloat16(v3)};
            *reinterpret_cast<uint2*>(S + (size_t)n * KPAD + lane * 4) =
                *reinterpret_cast<uint2*>(t4);
        } else if (lane < KPAD / 4) {           // K-pad 200..223 -> zero
            bf16 z4[4] = {};
            *reinterpret_cast<uint2*>(S + (size_t)n * KPAD + lane * 4) =
                *reinterpret_cast<uint2*>(z4);
        }
    }
}

// ---------------------------------------------------------------------------
// Fused: blocks [0,BATCH) build X rows; blocks [BATCH, BATCH+KPAD) build Wb.
// ---------------------------------------------------------------------------
__global__ void k_build_XW(const bf16* __restrict__ S, const float* __restrict__ rel_emb,
                           const float* __restrict__ time_emb, const float* __restrict__ dec_W,
                           const int* __restrict__ batch, bf16* __restrict__ X,
                           bf16* __restrict__ Wb) {
    int b = blockIdx.x;
    if (b < BATCH) {
        int m = b;
        int e  = batch[m * 4 + 0];
        int rl = batch[m * 4 + 1];
        int tr = batch[m * 4 + 3];
        float tv = time_emb[tr / 24];
        for (int c = threadIdx.x; c < XP; c += 256) {
            float v;
            if (c < HIDDEN) {
                v = tanhf(__bfloat162float(S[(size_t)e * KPAD + c]));
            } else if (c < 2 * HIDDEN) {
                v = rel_emb[(size_t)rl * HIDDEN + (c - HIDDEN)];
            } else if (c == 2 * HIDDEN) {
                v = tv;
            } else {
                v = 0.f;
            }
            X[(size_t)m * XP + c] = __float2bfloat16(v);
        }
    } else {
        int n = b - BATCH;
        for (int c = threadIdx.x; c < XP; c += 256) {
            float v = (n < HIDDEN && c < XDIM) ? dec_W[(size_t)n * XDIM + c] : 0.f;
            Wb[(size_t)n * XP + c] = __float2bfloat16(v);
        }
    }
}

// ---------------------------------------------------------------------------
// Y[4096][224] bf16 = relu( X(4096x416) . Wb^T(416x224) + b ), MFMA 16x16x32.
// ---------------------------------------------------------------------------
__global__ __launch_bounds__(256) void k_dec_gemm(const bf16* __restrict__ Xb,
                                                  const bf16* __restrict__ Wbb,
                                                  const float* __restrict__ dec_b,
                                                  bf16* __restrict__ Y) {
    int wid  = threadIdx.x >> 6;
    int lane = threadIdx.x & 63;
    int row0 = blockIdx.x * 64 + wid * 16;
    int rsel = lane & 15;
    int koff = (lane >> 4) * 8;

    const short* Xp = reinterpret_cast<const short*>(Xb);
    const short* Wp = reinterpret_cast<const short*>(Wbb);

    f32x4 acc[14] = {};
#pragma unroll
    for (int kt = 0; kt < 13; ++kt) {
        int kbase = kt * 32 + koff;
        bf16x8 a = *reinterpret_cast<const bf16x8*>(Xp + (size_t)(row0 + rsel) * XP + kbase);
#pragma unroll
        for (int j = 0; j < 14; ++j) {
            bf16x8 b = *reinterpret_cast<const bf16x8*>(Wp + (size_t)(j * 16 + rsel) * XP + kbase);
            acc[j] = __builtin_amdgcn_mfma_f32_16x16x32_bf16(a, b, acc[j], 0, 0, 0);
        }
    }

    int crow = (lane >> 4) * 4;     // C/D: col=lane&15, row=(lane>>4)*4+r
    int ccol = lane & 15;
#pragma unroll
    for (int j = 0; j < 14; ++j) {
        int col = j * 16 + ccol;
        float bias = (col < HIDDEN) ? dec_b[col] : 0.f;
#pragma unroll
        for (int r = 0; r < 4; ++r) {
            int row = row0 + crow + r;
            float v = fmaxf(acc[j][r] + bias, 0.f);
            Y[(size_t)row * KPAD + col] = __float2bfloat16(v);
        }
    }
}

// ---------------------------------------------------------------------------
// out[4096][30000] (f32) = Y(4096x224) . S^T(224x30208pad), bf16 MFMA.
// 256x256 tile, 8 waves, row-band-major, nt stores (R14 config) — but the
// epilogue is now BARRIER-FREE: each wave bounces through its private LDS
// buffer eb[wid] (in-wave lgkmcnt ordering only). No __syncthreads ->
// no `s_waitcnt vmcnt(0)` drains of the nt-store stream; stores stay
// fire-and-forget and pipeline across all 4 chunks.
// ---------------------------------------------------------------------------
__global__ __launch_bounds__(512, 2) void k_gemm(const bf16* __restrict__ Yb,
                                                 const bf16* __restrict__ Sb,
                                                 float* __restrict__ out) {
    __shared__ float eb[8][32 * 68];            // 69,632 B: per-wave bounce

    int bid   = blockIdx.x;                 // 0..1887
    int xtile = bid % 118;                  // N tile (FAST -> row-band concurrency)
    int ytile = bid / 118;                  // M tile (slow), 0..15

    int tid  = threadIdx.x;
    int wid  = tid >> 6;                    // 0..7
    int lane = tid & 63;
    int wm = wid >> 2, wn = wid & 3;
    int row0 = ytile * 256 + wm * 128;
    int col0 = xtile * 256 + wn * 64;
    int rsel = lane & 15;
    int koff = (lane >> 4) * 8;

    const short* Yp = reinterpret_cast<const short*>(Yb);
    const short* Sp = reinterpret_cast<const short*>(Sb);

    f32x4 acc[8][4] = {};
#pragma unroll
    for (int kt = 0; kt < 7; ++kt) {
        int kbase = kt * 32 + koff;
        bf16x8 a[8], b[4];
#pragma unroll
        for (int i = 0; i < 8; ++i)
            a[i] = *reinterpret_cast<const bf16x8*>(Yp + (size_t)(row0 + i * 16 + rsel) * KPAD + kbase);
#pragma unroll
        for (int j = 0; j < 4; ++j)
            b[j] = *reinterpret_cast<const bf16x8*>(Sp + (size_t)(col0 + j * 16 + rsel) * KPAD + kbase);
#pragma unroll
        for (int i = 0; i < 8; ++i)
#pragma unroll
            for (int j = 0; j < 4; ++j)
                acc[i][j] = __builtin_amdgcn_mfma_f32_16x16x32_bf16(a[i], b[j], acc[i][j], 0, 0, 0);
    }

    // Barrier-free per-wave epilogue: 4 chunks of 32 rows x 64 cols.
    float* myeb = eb[wid];
    int hi16 = lane >> 4;
    int lo16 = lane & 15;
#pragma unroll
    for (int h = 0; h < 4; ++h) {
#pragma unroll
        for (int ii = 0; ii < 2; ++ii)
#pragma unroll
            for (int j = 0; j < 4; ++j)
#pragma unroll
                for (int r = 0; r < 4; ++r)
                    myeb[(ii * 16 + hi16 * 4 + r) * 68 + j * 16 + lo16] = acc[h * 2 + ii][j][r];
#pragma unroll
        for (int q = 0; q < 8; ++q) {
            int lr = q * 4 + hi16;          // 0..31
            int lc = lo16 * 4;              // 0..60
            f32x4 v = *reinterpret_cast<f32x4*>(&myeb[lr * 68 + lc]);
            int grow = row0 + h * 32 + lr;
            int gcol = col0 + lc;
            if (gcol < NUM_ENT)             // 30000%4==0: all-or-nothing per f32x4
                __builtin_nontemporal_store(v,
                    reinterpret_cast<f32x4*>(&out[(size_t)grow * NUM_ENT + gcol]));
        }
    }
}

// ---------------------------------------------------------------------------
extern "C" void kernel_launch(void* const* d_in, const int* in_sizes, int n_in,
                              void* d_out, int out_size, void* d_ws, size_t ws_size,
                              hipStream_t stream) {
    const float* ent_emb  = (const float*)d_in[0];
    const float* attr_emb = (const float*)d_in[1];
    const float* rel_emb  = (const float*)d_in[2];
    const float* time_emb = (const float*)d_in[3];
    const float* rgcn_w   = (const float*)d_in[4];
    const float* dec_W    = (const float*)d_in[5];
    const float* dec_b    = (const float*)d_in[6];
    const float* norm     = (const float*)d_in[7];
    const int*   esrc     = (const int*)d_in[8];
    const int*   edst     = (const int*)d_in[9];
    const int*   etype    = (const int*)d_in[10];
    const int*   batch    = (const int*)d_in[11];

    char* ws = (char*)d_ws;
    bf16*   S      = (bf16*)ws;                           // 30208*224*2 = 13,533,184 B
    bf16*   Y      = (bf16*)(ws + 13533184);              //  1,835,008 B
    int*    offs   = (int*)(ws + 15368192);               //    120,064 B
    int*    cursor = (int*)(ws + 15488256);               //    120,064 B
    int*    sorted = (int*)(ws + 15608320);               //  2,520,000 B
    bf16*   X      = (bf16*)(ws + 18128320);              //  3,407,872 B (4096x416)
    bf16*   Wb     = (bf16*)(ws + 21536192);              //    186,368 B (224x416)
    ushort* h0b    = (ushort*)(ws + 21722560);            // 16,000,000 B (40000x200)

    k_cvt_prep<<<1 + (NUM_NODES * HIDDEN / 4 + 1023) / 1024, 1024, 0, stream>>>(
        ent_emb, attr_emb, norm, h0b, offs, cursor);
    k_place<<<(N_EDGES + 255) / 256, 256, 0, stream>>>(edst, esrc, etype, cursor, sorted);
    k_aggregate<<<NPAD2 / 2, 256, 0, stream>>>(h0b, rgcn_w, offs, cursor, sorted, norm, S);
    k_build_XW<<<BATCH + KPAD, 256, 0, stream>>>(S, rel_emb, time_emb, dec_W, batch, X, Wb);
    k_dec_gemm<<<BATCH / 64, 256, 0, stream>>>(X, Wb, dec_b, Y);
    k_gemm<<<118 * 16, 512, 0, stream>>>(Y, S, (float*)d_out);
}